// Round 7
// baseline (58155.634 us; speedup 1.0000x reference)
//
#include <hip/hip_runtime.h>

// ============================================================================
// 2-layer GRU RNN, persistent cooperative kernel. B=64, S=512, I=512, H=1024.
// Round 7: shrink the grid barrier (the ~4.7us/barrier fixed cost left in R6).
//  - 64 WGs total: layer(2) x group(4) x n8(8 slices of 128 cols), 512 thr.
//    Barrier groups of 16 arrivals (was 64).
//  - Waves = ntile-pair(4) x k-half(2): coherent A traffic 21 -> 5.2 MB/step,
//    one 16KB LDS reduction stage.
//  - Exact per-XCD weight partitioning: XCD x holds (L0,n8=x)+(L1,n8=x)
//    = 2.75 MB -> truly L2-resident (R6's mapping thrashed ~1GB/dispatch).
//  - Coherent h exchange via 16B sc0sc1 loads / 8B sc0sc1 stores (R6 scheme).
// ============================================================================

typedef _Float16 f16;
typedef f16  f16x8 __attribute__((ext_vector_type(8)));
typedef float f32x4 __attribute__((ext_vector_type(4)));
typedef unsigned long long u64;

#define NB   64
#define SEQ  512
#define IDIM 512
#define HDIM 1024
#define NBH  (NB*HDIM)

// workspace layout (bytes)
#define OFF_H0   0u             // f16 [2][64][1024] = 262144  (coherent mirror)
#define OFF_H1   262144u        // f16 [2][64][1024]
#define OFF_H0R  524288u        // f16 [64][1024]    = 131072  (h*r broadcast)
#define OFF_H1R  655360u        // f16 [64][1024]
#define OFF_BAR  786432u        // 4 groups x 1KB (cnt @ +0, gen @ +256)
#define OFF_W16  790528u        // f16 frag-order weights, L0 then L1
#define W16_L0_ELEMS 4718592u   // 3*1024*1536 (L1 starts here)

// LDS: red 16K | zst 8K | hst 4K | hf 8K  = 36864 (exact, verified)
#define SMEM_BYTES 36864

__device__ __forceinline__ float sigf(float x){ return 1.0f/(1.0f+__expf(-x)); }
__device__ __forceinline__ float tanh_fast(float x){ float e=__expf(2.0f*x); return 1.0f - 2.0f/(e+1.0f); }

// 16B coherent load (bypass L1/L2, read LLC). Not vmcnt-tracked by compiler;
// batch then explicit s_waitcnt vmcnt(0).
__device__ __forceinline__ f16x8 cload16(const f16* p){
  f16x8 r;
  asm volatile("global_load_dwordx4 %0, %1, off sc0 sc1" : "=v"(r) : "v"(p));
  return r;
}
// 8B coherent write-through store
__device__ __forceinline__ void cstore8(f16* p, u64 v){
  asm volatile("global_store_dwordx2 %0, %1, off sc0 sc1" :: "v"(p), "v"(v) : "memory");
}

// x fp32 -> f16 fragment (plain cached loads; x is read-only)
__device__ __forceinline__ f16x8 load_x_frag(const float* p){
  f32x4 v0 = *(const f32x4*)p;
  f32x4 v1 = *(const f32x4*)(p+4);
  f16x8 r;
  r[0]=(f16)v0[0]; r[1]=(f16)v0[1]; r[2]=(f16)v0[2]; r[3]=(f16)v0[3];
  r[4]=(f16)v1[0]; r[5]=(f16)v1[1]; r[6]=(f16)v1[2]; r[7]=(f16)v1[3];
  return r;
}

// flat 16-WG barrier, monotonic, all-relaxed (no cache maintenance)
__device__ __forceinline__ void group_barrier(char* gb, unsigned& lgen){
  asm volatile("s_waitcnt vmcnt(0) lgkmcnt(0)" ::: "memory");
  __syncthreads();
  if (threadIdx.x == 0){
    unsigned* cnt = (unsigned*)gb;
    unsigned* gen = (unsigned*)(gb + 256);
    const unsigned tgt = lgen + 1u;
    unsigned old = __hip_atomic_fetch_add(cnt, 1u, __ATOMIC_RELAXED, __HIP_MEMORY_SCOPE_AGENT);
    if (old == tgt*16u - 1u){
      __hip_atomic_store(gen, tgt, __ATOMIC_RELAXED, __HIP_MEMORY_SCOPE_AGENT);
    }
    while (__hip_atomic_load(gen, __ATOMIC_RELAXED, __HIP_MEMORY_SCOPE_AGENT) < tgt){
      __builtin_amdgcn_s_sleep(1);
    }
    lgen = tgt;
  }
  __syncthreads();
}

template<int LAYER>
__device__ void run_rnn(int g, int n8, const float* x,
    const float* brp, const float* bzp, const float* bcp,
    char* ws, char* smem, char* gb){
  constexpr int K   = (LAYER==0) ? 1536 : 2048;
  constexpr int NKS = K/32;          // 48 | 64 ksteps
  constexpr int KW  = NKS/2;         // 24 | 32 per k-half
  const int tid  = threadIdx.x;
  const int lane = tid & 63;
  const int wv   = tid >> 6;         // 0..7
  const int ntp  = wv & 3;           // ntile-pair (32 cols)
  const int kh   = wv >> 2;          // k-half
  const int quad = lane >> 4;
  const int qo   = quad*8;
  const int m_base = g*16;
  const int n_base = n8*128;
  const int arow   = m_base + (lane & 15);

  f32x4* red = (f32x4*)smem;                 // [16][64] f32x4 = 16384 B
  float* zst = (float*)(smem + 16384);       // [16][128] f32  =  8192 B
  f16*   hst = (f16*)  (smem + 24576);       // [16][128] f16  =  4096 B
  float* hf  = (float*)(smem + 28672);       // [16][128] f32  =  8192 B (end 36864)

#pragma unroll
  for (int i=0;i<4;++i) hf[tid + i*512] = 0.f;   // 2048 elems
  __syncthreads();

  f16* h0m = (f16*)(ws + OFF_H0);
  f16* h1m = (f16*)(ws + OFF_H1);
  f16* h0r = (f16*)(ws + OFF_H0R);
  f16* h1r = (f16*)(ws + OFF_H1R);
  f16* hrbuf = (LAYER==0)? h0r : h1r;
  f16* hown  = (LAYER==0)? h0m : h1m;
  const char* w16L = ws + OFF_W16 + (LAYER ? (size_t)W16_L0_ELEMS*2 : 0);

  // weight frag base ptrs: layout [gate][ntile(64)][kstep][lane*16B], 1KB/kstep
  const size_t lo = (size_t)lane*16;
  const int nt0 = n8*8 + ntp*2, nt1 = nt0 + 1;
  const char* bR0 = w16L + ((size_t)((0*64 + nt0)*NKS + kh*KW))*1024 + lo;
  const char* bR1 = w16L + ((size_t)((0*64 + nt1)*NKS + kh*KW))*1024 + lo;
  const char* bZ0 = w16L + ((size_t)((1*64 + nt0)*NKS + kh*KW))*1024 + lo;
  const char* bZ1 = w16L + ((size_t)((1*64 + nt1)*NKS + kh*KW))*1024 + lo;
  const char* bC0 = w16L + ((size_t)((2*64 + nt0)*NKS + kh*KW))*1024 + lo;
  const char* bC1 = w16L + ((size_t)((2*64 + nt1)*NKS + kh*KW))*1024 + lo;

  // local / global cols this lane owns in the epilogue (kh==0 waves)
  const int cl0 = ntp*32 + (lane & 15), cl1 = cl0 + 16;
  const int c0  = n_base + cl0,         c1  = n_base + cl1;
  const float bRv0 = brp[c0], bRv1 = brp[c1];
  const float bZv0 = bzp[c0], bZv1 = bzp[c1];
  const float bCv0 = bcp[c0], bCv1 = bcp[c1];

  unsigned lgen = 0;
  f16x8 fa[KW];

  for (int iter = 0; iter <= SEQ; ++iter){
    const int  t    = (LAYER==0) ? iter : (iter-1);
    const bool act  = (LAYER==0) ? (iter < SEQ) : (iter >= 1);
    const int  bufA = (iter & 1) ^ 1;

    // ================= PHASE A : pre_r, pre_z =================
    f32x4 aR0{0,0,0,0}, aR1{0,0,0,0}, aZ0{0,0,0,0}, aZ1{0,0,0,0};
    if (act){
      if (LAYER==0){
        const f16* h0s = h0m + (size_t)bufA*NBH + (size_t)arow*HDIM;
        if (kh==0){
#pragma unroll
          for (int j=0;j<16;++j)
            fa[j] = load_x_frag(x + ((size_t)arow*SEQ + t)*IDIM + j*32 + qo);
#pragma unroll
          for (int j=16;j<24;++j)
            fa[j] = cload16(h0s + (j-16)*32 + qo);
        } else {
#pragma unroll
          for (int j=0;j<24;++j)
            fa[j] = cload16(h0s + (8+j)*32 + qo);
        }
      } else {
        if (kh==0){
          const f16* p = h0m + (size_t)bufA*NBH + (size_t)arow*HDIM;
#pragma unroll
          for (int j=0;j<32;++j) fa[j] = cload16(p + j*32 + qo);
        } else {
          const f16* p = h1m + (size_t)(iter&1)*NBH + (size_t)arow*HDIM;
#pragma unroll
          for (int j=0;j<32;++j) fa[j] = cload16(p + j*32 + qo);
        }
      }
      asm volatile("s_waitcnt vmcnt(0)" ::: "memory");
#pragma unroll
      for (int j=0;j<KW;++j){
        aR0 = __builtin_amdgcn_mfma_f32_16x16x32_f16(fa[j], *(const f16x8*)(bR0 + j*1024), aR0,0,0,0);
        aR1 = __builtin_amdgcn_mfma_f32_16x16x32_f16(fa[j], *(const f16x8*)(bR1 + j*1024), aR1,0,0,0);
        aZ0 = __builtin_amdgcn_mfma_f32_16x16x32_f16(fa[j], *(const f16x8*)(bZ0 + j*1024), aZ0,0,0,0);
        aZ1 = __builtin_amdgcn_mfma_f32_16x16x32_f16(fa[j], *(const f16x8*)(bZ1 + j*1024), aZ1,0,0,0);
      }
      if (kh==1){
        red[(ntp*4+0)*64+lane] = aR0;  red[(ntp*4+1)*64+lane] = aR1;
        red[(ntp*4+2)*64+lane] = aZ0;  red[(ntp*4+3)*64+lane] = aZ1;
      }
    }
    __syncthreads();
    if (act && kh==0){
      aR0 += red[(ntp*4+0)*64+lane];  aR1 += red[(ntp*4+1)*64+lane];
      aZ0 += red[(ntp*4+2)*64+lane];  aZ1 += red[(ntp*4+3)*64+lane];
#pragma unroll
      for (int i=0;i<4;++i){
        int rowl = quad*4 + i;
        float r0 = sigf(aR0[i] + bRv0);
        float r1 = sigf(aR1[i] + bRv1);
        hst[rowl*128 + cl0] = (f16)(hf[rowl*128 + cl0] * r0);
        hst[rowl*128 + cl1] = (f16)(hf[rowl*128 + cl1] * r1);
        zst[rowl*128 + cl0] = sigf(aZ0[i] + bZv0);
        zst[rowl*128 + cl1] = sigf(aZ1[i] + bZv1);
      }
    }
    __syncthreads();
    if (act){                                   // publish h*r (all 512 thr, 8B each)
      int rowl = tid >> 5, cc = (tid & 31)*4;
      u64 v = *(const u64*)(hst + rowl*128 + cc);
      cstore8(hrbuf + (size_t)(m_base+rowl)*HDIM + n_base + cc, v);
    }
    group_barrier(gb, lgen);

    // ================= PHASE B : candidate + h update =================
    f32x4 aC0{0,0,0,0}, aC1{0,0,0,0};
    if (act){
      if (LAYER==0){
        const f16* p = h0r + (size_t)arow*HDIM;
        if (kh==0){
#pragma unroll
          for (int j=16;j<24;++j) fa[j] = cload16(p + (j-16)*32 + qo);  // x held
        } else {
#pragma unroll
          for (int j=0;j<24;++j)  fa[j] = cload16(p + (8+j)*32 + qo);
        }
      } else {
        if (kh==1){                                // kh0: all h0 frags held
          const f16* p = h1r + (size_t)arow*HDIM;
#pragma unroll
          for (int j=0;j<32;++j) fa[j] = cload16(p + j*32 + qo);
        }
      }
      asm volatile("s_waitcnt vmcnt(0)" ::: "memory");
#pragma unroll
      for (int j=0;j<KW;++j){
        aC0 = __builtin_amdgcn_mfma_f32_16x16x32_f16(fa[j], *(const f16x8*)(bC0 + j*1024), aC0,0,0,0);
        aC1 = __builtin_amdgcn_mfma_f32_16x16x32_f16(fa[j], *(const f16x8*)(bC1 + j*1024), aC1,0,0,0);
      }
      if (kh==1){
        red[(ntp*2+0)*64+lane] = aC0;  red[(ntp*2+1)*64+lane] = aC1;
      }
    }
    __syncthreads();
    if (act && kh==0){
      aC0 += red[(ntp*2+0)*64+lane];  aC1 += red[(ntp*2+1)*64+lane];
#pragma unroll
      for (int i=0;i<4;++i){
        int rowl = quad*4 + i;
        float can0 = tanh_fast(aC0[i] + bCv0);
        float can1 = tanh_fast(aC1[i] + bCv1);
        float z0 = zst[rowl*128 + cl0];
        float z1 = zst[rowl*128 + cl1];
        float h0v = hf[rowl*128 + cl0], h1v = hf[rowl*128 + cl1];
        float hn0 = h0v*z0 + (1.0f - z0)*can0;
        float hn1 = h1v*z1 + (1.0f - z1)*can1;
        hf[rowl*128 + cl0] = hn0;  hst[rowl*128 + cl0] = (f16)hn0;
        hf[rowl*128 + cl1] = hn1;  hst[rowl*128 + cl1] = (f16)hn1;
      }
    }
    __syncthreads();
    if (act){                                   // publish h (all 512 thr, 8B each)
      const int bufW = (LAYER==0) ? (iter&1) : ((iter&1)^1);
      int rowl = tid >> 5, cc = (tid & 31)*4;
      u64 v = *(const u64*)(hst + rowl*128 + cc);
      cstore8(hown + (size_t)bufW*NBH + (size_t)(m_base+rowl)*HDIM + n_base + cc, v);
    }
    group_barrier(gb, lgen);
  }
}

__global__ void __launch_bounds__(512, 2)
rnn_kernel(const float* x,
           const float* br0, const float* bz0, const float* bc0,
           const float* br1, const float* bz1, const float* bc1,
           const float* Wreg, const float* breg,
           float* out, char* ws){
  extern __shared__ char smem[];
  const int b = blockIdx.x;                   // 0..63
  // XCD partitioning: XCD x hosts slices (L0,n8=x) and (L1,n8=x) x 4 groups
  const int xcd = b & 7, slot = b >> 3;       // slot 0..7
  const int g = slot & 3, sh = slot >> 2;     // sh 0..1
  const int s = sh*8 + xcd;                   // 0..15 unique (layer,n8)
  const int layer = s >> 3, n8 = s & 7;
  char* gb = ws + OFF_BAR + (size_t)g*1024;

  if (layer==0) run_rnn<0>(g, n8, x, br0,bz0,bc0, ws, smem, gb);
  else          run_rnn<1>(g, n8, x, br1,bz1,bc1, ws, smem, gb);

  // regressor: one L1 WG per group handles its 16 rows (final h1 in buf 1)
  if (layer==1 && n8==0 && threadIdx.x < 32){
    int mrow = g*16 + ((int)threadIdx.x >> 1), o = threadIdx.x & 1;
    const f16* hp = (const f16*)(ws + OFF_H1) + (size_t)NBH + (size_t)mrow*HDIM;
    const float* wp = Wreg + (size_t)o*HDIM;
    float acc = 0.f;
#pragma unroll 4
    for (int k=0;k<HDIM;k+=4){
      u64 q = __hip_atomic_load((const u64*)(hp+k), __ATOMIC_RELAXED, __HIP_MEMORY_SCOPE_AGENT);
      union { u64 qq; f16 h[4]; } u; u.qq = q;
      acc += (float)u.h[0]*wp[k]   + (float)u.h[1]*wp[k+1]
           + (float)u.h[2]*wp[k+2] + (float)u.h[3]*wp[k+3];
    }
    out[mrow*2 + o] = acc + breg[o];
  }
}

// weights fp32 row-major [n][k] -> fp16 MFMA-frag order
// [layer][gate][ntile(64)][kstep][lane(64)][e(8)]; dst flat index == thread id
__global__ void prep_w(const float* Wr0, const float* Wz0, const float* Wc0,
                       const float* Wr1, const float* Wz1, const float* Wc1,
                       f16* w16){
  size_t i = (size_t)blockIdx.x*256 + threadIdx.x;
  const bool l1 = (i >= (size_t)W16_L0_ELEMS);
  size_t j = l1 ? i - (size_t)W16_L0_ELEMS : i;
  const int K   = l1 ? 2048 : 1536;
  const int NKS = K >> 5;
  int e    = (int)(j & 7);
  int lane = (int)((j >> 3) & 63);
  size_t r = j >> 9;
  int ks   = (int)(r % (size_t)NKS);
  size_t gnt = r / (size_t)NKS;
  int nt   = (int)(gnt & 63);
  int gate = (int)(gnt >> 6);
  int n = nt*16 + (lane & 15);
  int k = ks*32 + ((lane >> 4) << 3) + e;
  const float* W = l1 ? (gate==0 ? Wr1 : gate==1 ? Wz1 : Wc1)
                      : (gate==0 ? Wr0 : gate==1 ? Wz0 : Wc0);
  w16[i] = (f16)W[(size_t)n*K + k];
}

extern "C" void kernel_launch(void* const* d_in, const int* in_sizes, int n_in,
                              void* d_out, int out_size, void* d_ws, size_t ws_size,
                              hipStream_t stream){
  const float* x    = (const float*)d_in[0];
  const float* Wr0  = (const float*)d_in[1];
  const float* br0  = (const float*)d_in[2];
  const float* Wz0  = (const float*)d_in[3];
  const float* bz0  = (const float*)d_in[4];
  const float* Wc0  = (const float*)d_in[5];
  const float* bc0  = (const float*)d_in[6];
  const float* Wr1  = (const float*)d_in[7];
  const float* br1  = (const float*)d_in[8];
  const float* Wz1  = (const float*)d_in[9];
  const float* bz1  = (const float*)d_in[10];
  const float* Wc1  = (const float*)d_in[11];
  const float* bc1  = (const float*)d_in[12];
  const float* Wreg = (const float*)d_in[13];
  const float* breg = (const float*)d_in[14];
  float* out = (float*)d_out;
  char*  ws  = (char*)d_ws;

  // zero h mirrors + h*r buffers + barrier region
  hipMemsetAsync(ws, 0, OFF_W16, stream);

  // weights -> fp16 frag order (11010048 elems)
  prep_w<<<43008, 256, 0, stream>>>(Wr0, Wz0, Wc0, Wr1, Wz1, Wc1,
                                    (f16*)(ws + OFF_W16));

  hipFuncSetAttribute((const void*)rnn_kernel,
                      hipFuncAttributeMaxDynamicSharedMemorySize, 160*1024);

  void* args[] = { (void*)&x,
                   (void*)&br0, (void*)&bz0, (void*)&bc0,
                   (void*)&br1, (void*)&bz1, (void*)&bc1,
                   (void*)&Wreg, (void*)&breg,
                   (void*)&out, (void*)&ws };
  hipLaunchCooperativeKernel((const void*)rnn_kernel, dim3(64), dim3(512),
                             args, (unsigned)SMEM_BYTES, stream);
}

// Round 8
// 6968.462 us; speedup vs baseline: 8.3455x; 8.3455x over previous
//
#include <hip/hip_runtime.h>

// ============================================================================
// 2-layer GRU RNN, persistent cooperative kernel. B=64, S=512, I=512, H=1024.
// Round 8: R6 compute structure (256 WGs — weight-L2 residency verified by
//          FETCH counters; R7's 64-WG variant thrashed 15GB/dispatch) with
//          the two central grid barriers replaced by producer/consumer FLAGS:
//  - per-WG monotonic iter flags, 4 regions per group {A,B}x{L0,L1}, 32 u32.
//  - producer: publish slice -> s_waitcnt vmcnt(0) -> __syncthreads ->
//    tid0 stores iter+1 (relaxed agent, no cache maintenance).
//  - consumer: wave-0 lanes poll one flag each (2 regions in parallel via
//    lanes 0-31 / 32-63), then __syncthreads. Detection ~ one LLC round.
//  - waits: L0A: B_L0>=i | L1A: B_L0>=i & B_L1>=i | L0B: A_L0>=i+1 & A_L1>=i
//    (backpressure) | L1B: A_L1>=i+1. WAR-safe on parity mirrors + hr bufs.
// ============================================================================

typedef _Float16 f16;
typedef f16  f16x8 __attribute__((ext_vector_type(8)));
typedef float f32x4 __attribute__((ext_vector_type(4)));
typedef unsigned long long u64;

#define NB   64
#define SEQ  512
#define IDIM 512
#define HDIM 1024
#define NBH  (NB*HDIM)          // 65536 elems per h snapshot

// workspace layout (bytes)
#define OFF_H0   0u             // f16 [2][64][1024] = 262144  (coherent mirror)
#define OFF_H1   262144u        // f16 [2][64][1024]
#define OFF_H0R  524288u        // f16 [64][1024]    = 131072  (h*r broadcast)
#define OFF_H1R  655360u        // f16 [64][1024]
#define OFF_BAR  786432u        // 4 groups x 2KB flag block
#define OFF_W16  794624u        // f16 frag-order weights, L0 then L1
#define W16_L0_ELEMS 4718592u   // 3*1024*1536 (L1 starts here)

#define SMEM_BYTES 37888        // red 32K | zst 2K | hst 1K | hf 2K  (exact)

__device__ __forceinline__ float sigf(float x){ return 1.0f/(1.0f+__expf(-x)); }
__device__ __forceinline__ float tanh_fast(float x){ float e=__expf(2.0f*x); return 1.0f - 2.0f/(e+1.0f); }

// 16B coherent load (bypass L1/L2, read LLC). Not vmcnt-tracked by compiler;
// batch then explicit s_waitcnt vmcnt(0).
__device__ __forceinline__ f16x8 cload16(const f16* p){
  f16x8 r;
  asm volatile("global_load_dwordx4 %0, %1, off sc0 sc1" : "=v"(r) : "v"(p));
  return r;
}
// 8B coherent write-through store
__device__ __forceinline__ void cstore8(f16* p, u64 v){
  asm volatile("global_store_dwordx2 %0, %1, off sc0 sc1" :: "v"(p), "v"(v) : "memory");
}

// x fp32 -> f16 fragment (plain cached loads; x is read-only)
__device__ __forceinline__ f16x8 load_x_frag(const float* p){
  f32x4 v0 = *(const f32x4*)p;
  f32x4 v1 = *(const f32x4*)(p+4);
  f16x8 r;
  r[0]=(f16)v0[0]; r[1]=(f16)v0[1]; r[2]=(f16)v0[2]; r[3]=(f16)v0[3];
  r[4]=(f16)v1[0]; r[5]=(f16)v1[1]; r[6]=(f16)v1[2]; r[7]=(f16)v1[3];
  return r;
}

// Wait until all 32 flags of f0 >= t0 AND all 32 flags of f1 >= t1.
// Wave 0 polls (lane l<32 -> f0[l], l>=32 -> f1[l-32]); whole WG joins.
__device__ __forceinline__ void wait2(const unsigned* f0, unsigned t0,
                                      const unsigned* f1, unsigned t1){
  if (threadIdx.x < 64){
    const int l = threadIdx.x;
    const unsigned* p = (l < 32) ? (f0 + l) : (f1 + (l - 32));
    const unsigned tgt = (l < 32) ? t0 : t1;
    while (__hip_atomic_load(p, __ATOMIC_RELAXED, __HIP_MEMORY_SCOPE_AGENT) < tgt){
      __builtin_amdgcn_s_sleep(1);
    }
  }
  __syncthreads();
}

template<int LAYER>
__device__ void run_rnn(int g, int n32, const float* x,
    const float* brp, const float* bzp, const float* bcp,
    char* ws, char* smem, unsigned* fl){
  constexpr int K   = (LAYER==0) ? 1536 : 2048;
  constexpr int NKS = K/32;          // 48 | 64 ksteps
  constexpr int KW  = NKS/8;         // 6 | 8 ksteps per wave (kg-split 8)
  const int tid  = threadIdx.x;
  const int lane = tid & 63;
  const int kg   = tid >> 6;         // wave index = k-group 0..7
  const int quad = lane >> 4;
  const int qo   = quad*8;
  const int m_base = g*16;
  const int n_base = n32*32;
  const int arow   = m_base + (lane & 15);

  // flag regions: fl+0 A_L0 | fl+64 B_L0 | fl+128 A_L1 | fl+192 B_L1
  unsigned* myA = fl + (LAYER ? 128 : 0);
  unsigned* myB = fl + (LAYER ? 192 : 64);

  f32x4* red = (f32x4*)smem;                 // [4][8][64] f32x4 = 32768 B
  float* zst = (float*)(smem + 32768);       // [16][32] f32 = 2048 B
  f16*   hst = (f16*)  (smem + 34816);       // [16][32] f16 = 1024 B
  float* hf  = (float*)(smem + 35840);       // [16][32] f32 = 2048 B (ends 37888)

  hf[tid & 511] = 0.f;                       // 512 threads, 512 elems
  __syncthreads();

  f16* h0m = (f16*)(ws + OFF_H0);
  f16* h1m = (f16*)(ws + OFF_H1);
  f16* h0r = (f16*)(ws + OFF_H0R);
  f16* h1r = (f16*)(ws + OFF_H1R);
  f16* hrbuf = (LAYER==0)? h0r : h1r;
  f16* hown  = (LAYER==0)? h0m : h1m;
  const char* w16L = ws + OFF_W16 + (LAYER ? (size_t)W16_L0_ELEMS*2 : 0);

  // weight fragment base pointers: [gate][ntile][kstep][lane*16B], 1KB/kstep
  const size_t lo = (size_t)lane*16;
  const int nt0 = n32*2, nt1 = n32*2 + 1;
  const char* bR0 = w16L + ((size_t)((0*64 + nt0)*NKS + kg*KW))*1024 + lo;
  const char* bR1 = w16L + ((size_t)((0*64 + nt1)*NKS + kg*KW))*1024 + lo;
  const char* bZ0 = w16L + ((size_t)((1*64 + nt0)*NKS + kg*KW))*1024 + lo;
  const char* bZ1 = w16L + ((size_t)((1*64 + nt1)*NKS + kg*KW))*1024 + lo;
  const char* bC0 = w16L + ((size_t)((2*64 + nt0)*NKS + kg*KW))*1024 + lo;
  const char* bC1 = w16L + ((size_t)((2*64 + nt1)*NKS + kg*KW))*1024 + lo;

  // per-lane bias for this wave's owner role (ntile = kg&1)
  const int col_own = n_base + (kg & 1)*16 + (lane & 15);
  const float bRv = brp[col_own], bZv = bzp[col_own], bCv = bcp[col_own];

  f16x8 fa[KW];

  for (int iter = 0; iter <= SEQ; ++iter){
    const int  t    = (LAYER==0) ? iter : (iter-1);
    const bool act  = (LAYER==0) ? (iter < SEQ) : (iter >= 1);
    const int  bufA = (iter & 1) ^ 1;
    const unsigned ui = (unsigned)iter;

    // ---- phase A wait: h mirrors of step t ready ----
    if (LAYER==0) wait2(fl+64, ui, fl+64, ui);          // B_L0 >= iter
    else          wait2(fl+64, ui, fl+192, ui);         // B_L0, B_L1 >= iter

    // ================= PHASE A : pre_r, pre_z =================
    if (act){
#pragma unroll
      for (int j=0;j<KW;++j){
        int ks = kg*KW + j;
        if (LAYER==0){
          if (ks < 16)
            fa[j] = load_x_frag(x + ((size_t)arow*SEQ + t)*IDIM + ks*32 + qo);
          else
            fa[j] = cload16(h0m + (size_t)bufA*NBH + (size_t)arow*HDIM + (ks-16)*32 + qo);
        } else {
          if (ks < 32)
            fa[j] = cload16(h0m + (size_t)bufA*NBH + (size_t)arow*HDIM + ks*32 + qo);
          else
            fa[j] = cload16(h1m + (size_t)(iter&1)*NBH + (size_t)arow*HDIM + (ks-32)*32 + qo);
        }
      }
      asm volatile("s_waitcnt vmcnt(0)" ::: "memory");
      f32x4 aR0{0,0,0,0}, aR1{0,0,0,0}, aZ0{0,0,0,0}, aZ1{0,0,0,0};
#pragma unroll
      for (int j=0;j<KW;++j){
        aR0 = __builtin_amdgcn_mfma_f32_16x16x32_f16(fa[j], *(const f16x8*)(bR0 + j*1024), aR0,0,0,0);
        aR1 = __builtin_amdgcn_mfma_f32_16x16x32_f16(fa[j], *(const f16x8*)(bR1 + j*1024), aR1,0,0,0);
        aZ0 = __builtin_amdgcn_mfma_f32_16x16x32_f16(fa[j], *(const f16x8*)(bZ0 + j*1024), aZ0,0,0,0);
        aZ1 = __builtin_amdgcn_mfma_f32_16x16x32_f16(fa[j], *(const f16x8*)(bZ1 + j*1024), aZ1,0,0,0);
      }
      red[(0*8+kg)*64+lane] = aR0;  red[(1*8+kg)*64+lane] = aR1;
      red[(2*8+kg)*64+lane] = aZ0;  red[(3*8+kg)*64+lane] = aZ1;
    }
    __syncthreads();
    if (act && kg < 4){                      // owner waves: (gate, ntile)
      f32x4 s = red[(kg*8+0)*64+lane];
#pragma unroll
      for (int k2=1;k2<8;++k2) s += red[(kg*8+k2)*64+lane];
      const int coll = (kg&1)*16 + (lane&15);
#pragma unroll
      for (int i=0;i<4;++i){
        int rowl = quad*4 + i;
        if (kg < 2){                          // r gate -> h*r staged fp16
          float r = sigf(s[i] + bRv);
          hst[rowl*32 + coll] = (f16)(hf[rowl*32+coll] * r);
        } else {                              // z gate -> staged fp32
          zst[rowl*32 + coll] = sigf(s[i] + bZv);
        }
      }
    }
    __syncthreads();
    if (act && tid < 128){                    // publish h*r block (8B stores)
      int rowl = tid>>3, c8 = (tid&7)*4;
      u64 v = *(const u64*)(hst + rowl*32 + c8);
      cstore8(hrbuf + (size_t)(m_base+rowl)*HDIM + n_base + c8, v);
    }
    asm volatile("s_waitcnt vmcnt(0)" ::: "memory");
    __syncthreads();
    if (tid == 0)
      __hip_atomic_store(myA + n32, ui + 1u, __ATOMIC_RELAXED, __HIP_MEMORY_SCOPE_AGENT);

    // ---- phase B wait: h*r of step t ready (+ L0 backpressure on h0 buf) ----
    if (LAYER==0) wait2(fl+0,   ui+1u, fl+128, ui);     // A_L0>=i+1, A_L1>=i
    else          wait2(fl+128, ui+1u, fl+128, ui+1u);  // A_L1>=i+1

    // ================= PHASE B : candidate + h update =================
    if (act){
#pragma unroll
      for (int j=0;j<KW;++j){
        int ks = kg*KW + j;
        if (LAYER==0){
          if (ks >= 16)                       // x frags held from phase A
            fa[j] = cload16(h0r + (size_t)arow*HDIM + (ks-16)*32 + qo);
        } else {
          if (ks >= 32)                       // h0 frags held from phase A
            fa[j] = cload16(h1r + (size_t)arow*HDIM + (ks-32)*32 + qo);
        }
      }
      asm volatile("s_waitcnt vmcnt(0)" ::: "memory");
      f32x4 aC0{0,0,0,0}, aC1{0,0,0,0};
#pragma unroll
      for (int j=0;j<KW;++j){
        aC0 = __builtin_amdgcn_mfma_f32_16x16x32_f16(fa[j], *(const f16x8*)(bC0 + j*1024), aC0,0,0,0);
        aC1 = __builtin_amdgcn_mfma_f32_16x16x32_f16(fa[j], *(const f16x8*)(bC1 + j*1024), aC1,0,0,0);
      }
      red[(0*8+kg)*64+lane] = aC0;  red[(1*8+kg)*64+lane] = aC1;
    }
    __syncthreads();
    if (act && kg < 2){                       // owner waves: ntile = kg
      f32x4 s = red[(kg*8+0)*64+lane];
#pragma unroll
      for (int k2=1;k2<8;++k2) s += red[(kg*8+k2)*64+lane];
      const int coll = kg*16 + (lane&15);
#pragma unroll
      for (int i=0;i<4;++i){
        int rowl = quad*4 + i;
        float can = tanh_fast(s[i] + bCv);
        float z   = zst[rowl*32 + coll];
        float hnew = hf[rowl*32+coll]*z + (1.0f - z)*can;
        hf[rowl*32+coll]  = hnew;
        hst[rowl*32+coll] = (f16)hnew;
      }
    }
    __syncthreads();
    if (act && tid < 128){                    // publish h block
      const int bufW = (LAYER==0) ? (iter&1) : ((iter&1)^1);
      int rowl = tid>>3, c8 = (tid&7)*4;
      u64 v = *(const u64*)(hst + rowl*32 + c8);
      cstore8(hown + (size_t)bufW*NBH + (size_t)(m_base+rowl)*HDIM + n_base + c8, v);
    }
    asm volatile("s_waitcnt vmcnt(0)" ::: "memory");
    __syncthreads();
    if (tid == 0)
      __hip_atomic_store(myB + n32, ui + 1u, __ATOMIC_RELAXED, __HIP_MEMORY_SCOPE_AGENT);
  }
}

__global__ void __launch_bounds__(512, 2)
rnn_kernel(const float* x,
           const float* br0, const float* bz0, const float* bc0,
           const float* br1, const float* bz1, const float* bc1,
           const float* Wreg, const float* breg,
           float* out, char* ws){
  extern __shared__ char smem[];
  const int b = blockIdx.x;
  // XCD packing (R6-verified mapping — keeps per-XCD weight slice L2-resident)
  const int xcd = b & 7, slot = b >> 3;
  const int g = slot & 3, phi = slot >> 2;
  const int p = phi*8 + xcd;                  // 0..63 unique (layer, n32)
  const int layer = p >> 5, n32 = p & 31;
  unsigned* fl = (unsigned*)(ws + OFF_BAR + (size_t)g*2048);

  if (layer==0) run_rnn<0>(g, n32, x, br0,bz0,bc0, ws, smem, fl);
  else          run_rnn<1>(g, n32, x, br1,bz1,bc1, ws, smem, fl);

  // regressor: one L1 WG per group handles its 16 rows (h1 final in buf 1)
  if (layer==1 && n32==0){
    wait2(fl+192, (unsigned)SEQ + 1u, fl+192, (unsigned)SEQ + 1u); // all B_L1 done
    if (threadIdx.x < 32){
      int mrow = g*16 + ((int)threadIdx.x >> 1), o = threadIdx.x & 1;
      const f16* hp = (const f16*)(ws + OFF_H1) + (size_t)NBH + (size_t)mrow*HDIM;
      const float* wp = Wreg + (size_t)o*HDIM;
      float acc = 0.f;
#pragma unroll 4
      for (int k=0;k<HDIM;k+=4){
        u64 q = __hip_atomic_load((const u64*)(hp+k), __ATOMIC_RELAXED, __HIP_MEMORY_SCOPE_AGENT);
        union { u64 qq; f16 h[4]; } u; u.qq = q;
        acc += (float)u.h[0]*wp[k]   + (float)u.h[1]*wp[k+1]
             + (float)u.h[2]*wp[k+2] + (float)u.h[3]*wp[k+3];
      }
      out[mrow*2 + o] = acc + breg[o];
    }
  }
}

// weights fp32 row-major [n][k] -> fp16 MFMA-frag order
// [layer][gate][ntile(64)][kstep][lane(64)][e(8)]; dst flat index == thread id
__global__ void prep_w(const float* Wr0, const float* Wz0, const float* Wc0,
                       const float* Wr1, const float* Wz1, const float* Wc1,
                       f16* w16){
  size_t i = (size_t)blockIdx.x*256 + threadIdx.x;
  const bool l1 = (i >= (size_t)W16_L0_ELEMS);
  size_t j = l1 ? i - (size_t)W16_L0_ELEMS : i;
  const int K   = l1 ? 2048 : 1536;
  const int NKS = K >> 5;
  int e    = (int)(j & 7);
  int lane = (int)((j >> 3) & 63);
  size_t r = j >> 9;
  int ks   = (int)(r % (size_t)NKS);
  size_t gnt = r / (size_t)NKS;
  int nt   = (int)(gnt & 63);
  int gate = (int)(gnt >> 6);
  int n = nt*16 + (lane & 15);
  int k = ks*32 + ((lane >> 4) << 3) + e;
  const float* W = l1 ? (gate==0 ? Wr1 : gate==1 ? Wz1 : Wc1)
                      : (gate==0 ? Wr0 : gate==1 ? Wz0 : Wc0);
  w16[i] = (f16)W[(size_t)n*K + k];
}

extern "C" void kernel_launch(void* const* d_in, const int* in_sizes, int n_in,
                              void* d_out, int out_size, void* d_ws, size_t ws_size,
                              hipStream_t stream){
  const float* x    = (const float*)d_in[0];
  const float* Wr0  = (const float*)d_in[1];
  const float* br0  = (const float*)d_in[2];
  const float* Wz0  = (const float*)d_in[3];
  const float* bz0  = (const float*)d_in[4];
  const float* Wc0  = (const float*)d_in[5];
  const float* bc0  = (const float*)d_in[6];
  const float* Wr1  = (const float*)d_in[7];
  const float* br1  = (const float*)d_in[8];
  const float* Wz1  = (const float*)d_in[9];
  const float* bz1  = (const float*)d_in[10];
  const float* Wc1  = (const float*)d_in[11];
  const float* bc1  = (const float*)d_in[12];
  const float* Wreg = (const float*)d_in[13];
  const float* breg = (const float*)d_in[14];
  float* out = (float*)d_out;
  char*  ws  = (char*)d_ws;

  // zero h mirrors + h*r buffers + flag region
  hipMemsetAsync(ws, 0, OFF_W16, stream);

  // weights -> fp16 frag order (11010048 elems)
  prep_w<<<43008, 256, 0, stream>>>(Wr0, Wz0, Wc0, Wr1, Wz1, Wc1,
                                    (f16*)(ws + OFF_W16));

  hipFuncSetAttribute((const void*)rnn_kernel,
                      hipFuncAttributeMaxDynamicSharedMemorySize, 160*1024);

  void* args[] = { (void*)&x,
                   (void*)&br0, (void*)&bz0, (void*)&bc0,
                   (void*)&br1, (void*)&bz1, (void*)&bc1,
                   (void*)&Wreg, (void*)&breg,
                   (void*)&out, (void*)&ws };
  hipLaunchCooperativeKernel((const void*)rnn_kernel, dim3(256), dim3(512),
                             args, (unsigned)SMEM_BYTES, stream);
}